// Round 6
// baseline (365.280 us; speedup 1.0000x reference)
//
#include <hip/hip_runtime.h>
#include <stdint.h>

typedef unsigned short u16;
typedef unsigned int u32;
typedef __attribute__((ext_vector_type(2))) float f32x2;
typedef __attribute__((ext_vector_type(4))) float f32x4;
typedef __attribute__((ext_vector_type(4))) u32 u32x4;
typedef __attribute__((ext_vector_type(2))) u32 u32x2;
typedef __attribute__((ext_vector_type(8))) short bf16x8;

#define NKEYS 65536
#define DIM 1024
#define NCLS 103
#define NCAND 64
#define SROW 40     // padded LDS row stride in u16 (80 B; 5 bank-quads, coprime with 8)
#define NBLK 256
#define NTHR 512

__device__ __forceinline__ u16 f2bf(float x) {
  u32 u = __float_as_uint(x);
  u = u + 0x7FFFu + ((u >> 16) & 1u);
  return (u16)(u >> 16);
}
// packed f32x2 -> bf16x2; used identically on A and B packing so any intra-pair
// k-permutation cancels in the dot product.
__device__ __forceinline__ u32 cvtpk(float lo, float hi) {
  u32 d;
  asm("v_cvt_pk_bf16_f32 %0, %1, %2" : "=v"(d) : "v"(lo), "v"(hi));
  return d;
}

union SMEM {
  struct { float sAT[2][32][68]; float sBT[2][32][68]; } g;                 // ~35 KB
  struct { u16 sA[2][256 * SROW]; u16 sB[2][128 * SROW]; float snorm[128]; } s; // ~62 KB
  struct { int redc[8]; int sc1, sc2; int clist[NCAND];
           float sdq[NCAND], sdqt[NCAND], snr[NCAND];
           int srowi[32]; float sw[32]; float red1[8], red2[8];
           float smg[2048]; } t;                                            // ~10 KB
};

// device-scope grid barrier; cnt zeroed by hipMemsetAsync each launch; gen monotonic.
__device__ __forceinline__ void gridbar(u32* cnt, u32* gen) {
  __syncthreads();
  if (threadIdx.x == 0) {
    __threadfence();
    u32 g0 = __hip_atomic_load(gen, __ATOMIC_RELAXED, __HIP_MEMORY_SCOPE_AGENT);
    u32 old = __hip_atomic_fetch_add(cnt, 1u, __ATOMIC_ACQ_REL, __HIP_MEMORY_SCOPE_AGENT);
    if (old == NBLK - 1u) {
      __hip_atomic_store(cnt, 0u, __ATOMIC_RELAXED, __HIP_MEMORY_SCOPE_AGENT);
      __hip_atomic_fetch_add(gen, 1u, __ATOMIC_ACQ_REL, __HIP_MEMORY_SCOPE_AGENT);
    } else {
      while (__hip_atomic_load(gen, __ATOMIC_ACQUIRE, __HIP_MEMORY_SCOPE_AGENT) == g0)
        __builtin_amdgcn_s_sleep(2);
    }
    __threadfence();
  }
  __syncthreads();
}

// small fp32 NT-GEMM phase, split-K4: out[m][n] = sum_k A[m][k]*B[n][k]
// block b: n0=(b&15)*64, m0=((b>>4)&3)*64, kz=b>>6; 512 thr, 2x4 acc/thread.
__device__ __forceinline__ void small_gemm(const float* __restrict__ A,
                                           const float* __restrict__ B,
                                           float* __restrict__ partial,
                                           SMEM* sm, int b, int tid) {
  const int n0 = (b & 15) * 64;
  const int m0 = ((b >> 4) & 3) * 64;
  const int kz = (b >> 6) & 3;
  const int ar = tid & 63;
  const int kq = (tid >> 6) * 4;
  const int tx = tid & 15, ty = tid >> 4;
  float acc[2][4] = {};
  const float* ag = A + (size_t)(m0 + ar) * DIM + kz * 256 + kq;
  const float* bg = B + (size_t)(n0 + ar) * DIM + kz * 256 + kq;
  f32x4 av = *(const f32x4*)ag;
  f32x4 bv = *(const f32x4*)bg;
#pragma unroll
  for (int i = 0; i < 4; ++i) {
    sm->g.sAT[0][kq + i][ar] = av[i];
    sm->g.sBT[0][kq + i][ar] = bv[i];
  }
  __syncthreads();
  for (int kb = 0; kb < 8; ++kb) {
    const int cur = kb & 1;
    if (kb + 1 < 8) {
      av = *(const f32x4*)(ag + (kb + 1) * 32);
      bv = *(const f32x4*)(bg + (kb + 1) * 32);
    }
#pragma unroll
    for (int kk = 0; kk < 32; ++kk) {
      const f32x2 a2 = *(const f32x2*)&sm->g.sAT[cur][kk][ty * 2];
      const f32x4 b4 = *(const f32x4*)&sm->g.sBT[cur][kk][tx * 4];
#pragma unroll
      for (int i = 0; i < 2; ++i)
#pragma unroll
        for (int j = 0; j < 4; ++j) acc[i][j] += a2[i] * b4[j];
    }
    if (kb + 1 < 8) {
#pragma unroll
      for (int i = 0; i < 4; ++i) {
        sm->g.sAT[cur ^ 1][kq + i][ar] = av[i];
        sm->g.sBT[cur ^ 1][kq + i][ar] = bv[i];
      }
    }
    __syncthreads();
  }
#pragma unroll
  for (int i = 0; i < 2; ++i) {
    f32x4 ov = {acc[i][0], acc[i][1], acc[i][2], acc[i][3]};
    *(f32x4*)(partial + (size_t)kz * 262144u + (size_t)(m0 + ty * 2 + i) * DIM + n0 + tx * 4) = ov;
  }
}

// sum 4 split-K slabs + bias + relu; optional bf16 pack
__device__ __forceinline__ void reduce_phase(const float* __restrict__ partial,
                                             const float* __restrict__ bias,
                                             float* __restrict__ outf,
                                             u16* __restrict__ outb, int gid) {
  if (gid < 65536) {
    const int e = gid * 4;
    const int n = e & (DIM - 1);
    f32x4 s = *(const f32x4*)(partial + e);
    s += *(const f32x4*)(partial + 262144u + e);
    s += *(const f32x4*)(partial + 2u * 262144u + e);
    s += *(const f32x4*)(partial + 3u * 262144u + e);
    s += *(const f32x4*)(bias + n);
#pragma unroll
    for (int i = 0; i < 4; ++i) s[i] = fmaxf(s[i], 0.f);
    *(f32x4*)(outf + e) = s;
    if (outb) {
      u32x2 h = {cvtpk(s[0], s[1]), cvtpk(s[2], s[3])};
      *(u32x2*)(outb + e) = h;
    }
  }
}

__global__ __launch_bounds__(NTHR, 2) void mega(
    const float* __restrict__ query, const float* __restrict__ keys,
    const float* __restrict__ Wenc, const float* __restrict__ benc,
    const float* __restrict__ Wd, const float* __restrict__ bd,
    const float* __restrict__ lng, const float* __restrict__ lnb,
    const float* __restrict__ Wc, const float* __restrict__ bc,
    float* __restrict__ q, float* __restrict__ qt, u16* __restrict__ qb,
    float* __restrict__ par1, float* __restrict__ par2, u16* __restrict__ sim,
    u32* __restrict__ bar, float* __restrict__ out)
{
  __shared__ SMEM smem;
  SMEM* const sm = &smem;
  const int tid = threadIdx.x;
  const int b = blockIdx.x;
  const int lane = tid & 63, wave = tid >> 6;
  u32* cnt = bar;
  u32* gen = bar + 32;

  // ---- P1: q_partial = query @ Wenc^T
  small_gemm(query, Wenc, par1, sm, b, tid);
  gridbar(cnt, gen);
  // ---- R1: q = relu(sum + benc); qb = bf16(q)
  reduce_phase(par1, benc, q, qb, b * NTHR + tid);
  gridbar(cnt, gen);
  // ---- P2: qt_partial = q @ Wd^T
  small_gemm(q, Wd, par2, sm, b, tid);
  gridbar(cnt, gen);
  // ---- R2: qt = relu(sum + bd)
  reduce_phase(par2, bd, qt, (u16*)0, b * NTHR + tid);
  gridbar(cnt, gen);

  // ---- P3: sim = bf16( (q . key_n) / max(||key_n||,1e-8) ), 2 stripes of 128 keys
  {
    const int a_r = tid >> 1;
    const int a_h = (tid & 1) * 16;
    const u16* agp = qb + (size_t)a_r * DIM + a_h;
    const int a_ws = a_r * SROW + a_h;
    const int b_r = tid >> 2;
    const int b_q = (tid & 3) * 8;
    const int b_ws = b_r * SROW + b_q;
    const int wm = (wave >> 1) * 64;
    const int wn = (wave & 1) * 64;
    const int lr = lane & 15;
    const int lk = (lane >> 4) * 8;
    const int l4 = (lane >> 4) * 4;

    for (int s = 0; s < 2; ++s) {
      const int n0 = (b * 2 + s) * 128;
      const float* bgp = keys + (size_t)(n0 + b_r) * DIM + b_q;
      float nrm = 0.f;
      f32x4 acc[4][4];
#pragma unroll
      for (int i = 0; i < 4; ++i)
#pragma unroll
        for (int j = 0; j < 4; ++j) acc[i][j] = (f32x4){0.f, 0.f, 0.f, 0.f};

      f32x4 b00, b01, b10, b11, b20, b21, b30, b31;
      u32x4 a00, a01, a10, a11;

#define LOADB(B0, B1, T) do { \
    B0 = *(const f32x4*)(bgp + (size_t)(T) * 32); \
    B1 = *(const f32x4*)(bgp + (size_t)(T) * 32 + 4); \
  } while (0)
#define LOADA(A0, A1, T) do { \
    A0 = *(const u32x4*)(agp + (size_t)(T) * 32); \
    A1 = *(const u32x4*)(agp + (size_t)(T) * 32 + 8); \
  } while (0)
#define WRITE(B0, B1, A0, A1, BUF) do { \
    nrm += B0[0]*B0[0] + B0[1]*B0[1] + B0[2]*B0[2] + B0[3]*B0[3]; \
    nrm += B1[0]*B1[0] + B1[1]*B1[1] + B1[2]*B1[2] + B1[3]*B1[3]; \
    u32x4 bp; \
    bp.x = cvtpk(B0[0], B0[1]); bp.y = cvtpk(B0[2], B0[3]); \
    bp.z = cvtpk(B1[0], B1[1]); bp.w = cvtpk(B1[2], B1[3]); \
    *(u32x4*)&sm->s.sB[BUF][b_ws] = bp; \
    *(u32x4*)&sm->s.sA[BUF][a_ws] = A0; \
    *(u32x4*)&sm->s.sA[BUF][a_ws + 8] = A1; \
  } while (0)
#define COMPUTE(BUF) do { \
    bf16x8 af[4], bfr[4]; \
    _Pragma("unroll") \
    for (int f = 0; f < 4; ++f) { \
      af[f]  = *(const bf16x8*)&sm->s.sA[BUF][(wm + f * 16 + lr) * SROW + lk]; \
      bfr[f] = *(const bf16x8*)&sm->s.sB[BUF][(wn + f * 16 + lr) * SROW + lk]; \
    } \
    _Pragma("unroll") \
    for (int i = 0; i < 4; ++i) \
      _Pragma("unroll") \
      for (int j = 0; j < 4; ++j) \
        acc[i][j] = __builtin_amdgcn_mfma_f32_16x16x32_bf16(af[i], bfr[j], acc[i][j], 0, 0, 0); \
  } while (0)

      LOADB(b00, b01, 0); LOADB(b10, b11, 1); LOADB(b20, b21, 2); LOADB(b30, b31, 3);
      LOADA(a00, a01, 0); LOADA(a10, a11, 1);
      WRITE(b00, b01, a00, a01, 0);
      __syncthreads();

      for (int tt = 0; tt < 32; tt += 4) {
        if (tt + 4 < 32) LOADB(b00, b01, tt + 4);
        LOADA(a00, a01, tt + 2);
        COMPUTE(0);
        WRITE(b10, b11, a10, a11, 1);
        __syncthreads();
        if (tt + 5 < 32) LOADB(b10, b11, tt + 5);
        LOADA(a10, a11, tt + 3);
        COMPUTE(1);
        WRITE(b20, b21, a00, a01, 0);
        __syncthreads();
        if (tt + 6 < 32) LOADB(b20, b21, tt + 6);
        if (tt + 4 < 32) LOADA(a00, a01, tt + 4);
        COMPUTE(0);
        WRITE(b30, b31, a10, a11, 1);
        __syncthreads();
        if (tt + 7 < 32) LOADB(b30, b31, tt + 7);
        if (tt + 5 < 32) LOADA(a10, a11, tt + 5);
        COMPUTE(1);
        if (tt + 4 < 32) WRITE(b00, b01, a00, a01, 0);
        __syncthreads();
      }
#undef LOADB
#undef LOADA
#undef WRITE
#undef COMPUTE

      nrm += __shfl_xor(nrm, 1);
      nrm += __shfl_xor(nrm, 2);
      if ((tid & 3) == 0) sm->s.snorm[b_r] = nrm;
      __syncthreads();

#pragma unroll
      for (int j = 0; j < 4; ++j) {
        const int nl = wn + j * 16 + lr;
        const float scl = 1.f / fmaxf(sqrtf(sm->s.snorm[nl]), 1e-8f);
        const size_t ng = (size_t)(n0 + nl);
#pragma unroll
        for (int i = 0; i < 4; ++i) {
          const int mb = wm + i * 16 + l4;
#pragma unroll
          for (int r = 0; r < 4; ++r) {
            sim[(size_t)(mb + r) * NKEYS + ng] = f2bf(acc[i][j][r] * scl);
          }
        }
      }
      __syncthreads();
    }
  }
  gridbar(cnt, gen);

  // ---- P4: per-row top-64 -> exact rescore -> top-32 softmax attention -> LN -> classifier
  {
    const int m = b;
    const u32x4* row = (const u32x4*)(sim + (size_t)m * NKEYS);
    u32 ku[16][4];
#pragma unroll
    for (int i = 0; i < 16; ++i) {
      const u32x4 v = row[i * 512 + tid];
#pragma unroll
      for (int c = 0; c < 4; ++c) {
        u32 lo = v[c] & 0xFFFFu, hi = v[c] >> 16;
        lo ^= (lo & 0x8000u) ? 0xFFFFu : 0x8000u;
        hi ^= (hi & 0x8000u) ? 0xFFFFu : 0x8000u;
        ku[i][c] = lo | (hi << 16);
      }
    }
    int lo_b = 0, hi_b = 65536;
    while (hi_b - lo_b > 1) {
      const u32 mid = (u32)((lo_b + hi_b) >> 1);
      int c = 0;
#pragma unroll
      for (int i = 0; i < 16; ++i)
#pragma unroll
        for (int k = 0; k < 4; ++k) {
          const u32 x = ku[i][k];
          c += ((x & 0xFFFFu) >= mid) ? 1 : 0;
          c += ((x >> 16) >= mid) ? 1 : 0;
        }
#pragma unroll
      for (int j = 32; j; j >>= 1) c += __shfl_xor(c, j);
      if ((tid & 63) == 0) sm->t.redc[tid >> 6] = c;
      __syncthreads();
      int tot = 0;
#pragma unroll
      for (int w = 0; w < 8; ++w) tot += sm->t.redc[w];
      if (tot >= NCAND) lo_b = (int)mid; else hi_b = (int)mid;
      __syncthreads();
    }
    const u32 tau = (u32)lo_b;

    int ch = 0;
#pragma unroll
    for (int i = 0; i < 16; ++i)
#pragma unroll
      for (int k = 0; k < 4; ++k) {
        const u32 x = ku[i][k];
        ch += ((x & 0xFFFFu) > tau) ? 1 : 0;
        ch += ((x >> 16) > tau) ? 1 : 0;
      }
#pragma unroll
    for (int j = 32; j; j >>= 1) ch += __shfl_xor(ch, j);
    if ((tid & 63) == 0) sm->t.redc[tid >> 6] = ch;
    if (tid == 0) { sm->t.sc1 = 0; sm->t.sc2 = 0; }
    __syncthreads();
    int nhi = 0;
#pragma unroll
    for (int w = 0; w < 8; ++w) nhi += sm->t.redc[w];

#pragma unroll
    for (int i = 0; i < 16; ++i)
#pragma unroll
      for (int k = 0; k < 4; ++k) {
        const int nb = (i * 512 + tid) * 8 + k * 2;
        const u32 x = ku[i][k];
        const u32 l = x & 0xFFFFu, h = x >> 16;
        if (l > tau) { int p = atomicAdd(&sm->t.sc1, 1); sm->t.clist[p] = nb; }
        else if (l == tau) { int p = atomicAdd(&sm->t.sc2, 1); if (nhi + p < NCAND) sm->t.clist[nhi + p] = nb; }
        if (h > tau) { int p = atomicAdd(&sm->t.sc1, 1); sm->t.clist[p] = nb + 1; }
        else if (h == tau) { int p = atomicAdd(&sm->t.sc2, 1); if (nhi + p < NCAND) sm->t.clist[nhi + p] = nb + 1; }
      }
    __syncthreads();

    // exact fp32 rescore (8 candidates per wave)
    f32x4 q4[4], qt4[4];
#pragma unroll
    for (int i = 0; i < 4; ++i) {
      q4[i]  = *(const f32x4*)(q  + (size_t)m * DIM + i * 256 + lane * 4);
      qt4[i] = *(const f32x4*)(qt + (size_t)m * DIM + i * 256 + lane * 4);
    }
    for (int ci = 0; ci < 8; ++ci) {
      const int c = wave * 8 + ci;
      const float* kr = keys + (size_t)sm->t.clist[c] * DIM;
      float dq = 0.f, dt = 0.f, ss = 0.f;
#pragma unroll
      for (int i = 0; i < 4; ++i) {
        const f32x4 kv = *(const f32x4*)(kr + i * 256 + lane * 4);
#pragma unroll
        for (int e = 0; e < 4; ++e) {
          dq += kv[e] * q4[i][e];
          dt += kv[e] * qt4[i][e];
          ss += kv[e] * kv[e];
        }
      }
#pragma unroll
      for (int j = 32; j; j >>= 1) {
        dq += __shfl_xor(dq, j);
        dt += __shfl_xor(dt, j);
        ss += __shfl_xor(ss, j);
      }
      if (lane == 0) { sm->t.sdq[c] = dq; sm->t.sdqt[c] = dt; sm->t.snr[c] = ss; }
    }
    __syncthreads();

    // top-32 of 64 (bitonic on wave 0) + softmax weights
    if (wave == 0) {
      float v = sm->t.sdq[lane] / fmaxf(sqrtf(sm->t.snr[lane]), 1e-8f);
      int p = lane;
#pragma unroll
      for (int k = 2; k <= 64; k <<= 1)
#pragma unroll
        for (int j = k >> 1; j > 0; j >>= 1) {
          const float ov = __shfl_xor(v, j);
          const int op = __shfl_xor(p, j);
          const bool tl = ((lane & j) == 0) == ((lane & k) == 0);
          const bool take = tl ? (ov > v) : (ov < v);
          if (take) { v = ov; p = op; }
        }
      float sc = (lane < 32) ? sm->t.sdqt[p] : -3.4e38f;
      float mx = sc;
#pragma unroll
      for (int j = 16; j; j >>= 1) mx = fmaxf(mx, __shfl_xor(mx, j));
      const float e = (lane < 32) ? expf(sc - mx) : 0.f;
      float ssum = e;
#pragma unroll
      for (int j = 16; j; j >>= 1) ssum += __shfl_xor(ssum, j);
      if (lane < 32) { sm->t.sw[lane] = e / ssum; sm->t.srowi[lane] = sm->t.clist[p]; }
    }
    __syncthreads();

    // attention + residual + LayerNorm
    const int d0 = tid * 2;
    f32x2 at = {0.f, 0.f};
    for (int j = 0; j < 32; ++j) {
      const float wj = sm->t.sw[j];
      const f32x2 kv = *(const f32x2*)(keys + (size_t)sm->t.srowi[j] * DIM + d0);
      at += wj * kv;
    }
    const f32x2 qv = *(const f32x2*)(q + (size_t)m * DIM + d0);
    const f32x2 x = at + qv;
    float s1 = x[0] + x[1];
#pragma unroll
    for (int j = 32; j; j >>= 1) s1 += __shfl_xor(s1, j);
    if (lane == 0) sm->t.red1[wave] = s1;
    __syncthreads();
    float mu = 0.f;
#pragma unroll
    for (int w = 0; w < 8; ++w) mu += sm->t.red1[w];
    mu *= (1.f / 1024.f);
    const f32x2 xc = x - mu;
    float s2 = xc[0] * xc[0] + xc[1] * xc[1];
#pragma unroll
    for (int j = 32; j; j >>= 1) s2 += __shfl_xor(s2, j);
    if (lane == 0) sm->t.red2[wave] = s2;
    __syncthreads();
    float var = 0.f;
#pragma unroll
    for (int w = 0; w < 8; ++w) var += sm->t.red2[w];
    var *= (1.f / 1024.f);
    const float rstd = rsqrtf(var + 1e-5f);
    const f32x2 g = *(const f32x2*)(lng + d0);
    const f32x2 bb = *(const f32x2*)(lnb + d0);
    const f32x2 ma = xc * rstd * g + bb;
    *(f32x2*)&sm->t.smg[d0] = qv;
    *(f32x2*)&sm->t.smg[1024 + d0] = ma;
    __syncthreads();

    // classifier
    for (int c = wave; c < NCLS; c += 8) {
      const float* w = Wc + (size_t)c * 2048;
      float a = 0.f;
#pragma unroll
      for (int i = 0; i < 8; ++i) {
        const f32x4 wv = *(const f32x4*)(w + i * 256 + lane * 4);
        const f32x4 mv = *(const f32x4*)&sm->t.smg[i * 256 + lane * 4];
#pragma unroll
        for (int e = 0; e < 4; ++e) a += wv[e] * mv[e];
      }
#pragma unroll
      for (int j = 32; j; j >>= 1) a += __shfl_xor(a, j);
      if (lane == 0) out[(size_t)m * NCLS + c] = a + bc[c];
    }
  }
}

extern "C" void kernel_launch(void* const* d_in, const int* in_sizes, int n_in,
                              void* d_out, int out_size, void* d_ws, size_t ws_size,
                              hipStream_t stream)
{
  const float* query = (const float*)d_in[1];
  const float* keys  = (const float*)d_in[2];
  const float* Wenc  = (const float*)d_in[3];
  const float* benc  = (const float*)d_in[4];
  const float* Wd    = (const float*)d_in[5];
  const float* bd    = (const float*)d_in[6];
  const float* lng   = (const float*)d_in[7];
  const float* lnb   = (const float*)d_in[8];
  const float* Wcls  = (const float*)d_in[9];
  const float* bcls  = (const float*)d_in[10];
  float* out = (float*)d_out;
  char* ws = (char*)d_ws;

  // workspace layout (bytes); par slabs alias the head of sim (dead before P3 writes)
  float* q   = (float*)(ws + 0);              // 1 MB
  float* qt  = (float*)(ws + 1048576u);       // 1 MB
  u16*   qb  = (u16*)(ws + 2097152u);         // 0.5 MB
  u32*   bar = (u32*)(ws + 2621440u);         // 4 KB (cnt @ +0, gen @ +128)
  char*  big = ws + 2625536u;                 // 32 MB sim
  u16*   sim = (u16*)big;
  float* par1 = (float*)big;                  // 4 MB (P1 slabs, dead after R1)
  float* par2 = (float*)(big + 4194304u);     // 4 MB (P2 slabs, dead after R2)

  hipMemsetAsync(bar, 0, 256, stream);
  mega<<<NBLK, NTHR, 0, stream>>>(query, keys, Wenc, benc, Wd, bd, lng, lnb,
                                  Wcls, bcls, q, qt, qb, par1, par2, sim, bar, out);
}

// Round 7
// 300.287 us; speedup vs baseline: 1.2164x; 1.2164x over previous
//
#include <hip/hip_runtime.h>
#include <stdint.h>

typedef unsigned short u16;
typedef unsigned int u32;
typedef __attribute__((ext_vector_type(2))) float f32x2;
typedef __attribute__((ext_vector_type(4))) float f32x4;
typedef __attribute__((ext_vector_type(4))) u32 u32x4;
typedef __attribute__((ext_vector_type(2))) u32 u32x2;
typedef __attribute__((ext_vector_type(8))) short bf16x8;

#define NKEYS 65536
#define DIM 1024
#define NCLS 103
#define NCAND 64
#define SROW 40     // padded LDS row stride in u16 (80 B; 5 bank-quads, coprime with 8)
#define NBLK 256
#define NTHR 512

__device__ __forceinline__ u16 f2bf(float x) {
  u32 u = __float_as_uint(x);
  u = u + 0x7FFFu + ((u >> 16) & 1u);
  return (u16)(u >> 16);
}
// packed f32x2 -> bf16x2; used identically on A and B packing so any intra-pair
// k-permutation cancels in the dot product.
__device__ __forceinline__ u32 cvtpk(float lo, float hi) {
  u32 d;
  asm("v_cvt_pk_bf16_f32 %0, %1, %2" : "=v"(d) : "v"(lo), "v"(hi));
  return d;
}

union SMEM {
  struct { float sAT[2][32][68]; float sBT[2][32][68]; } g;                 // ~35 KB
  struct { u16 sA[2][256 * SROW]; u16 sB[2][128 * SROW]; float snorm[128]; } s; // ~62 KB
  struct { int redc[8]; int sc1, sc2; int clist[NCAND];
           float sdq[NCAND], sdqt[NCAND], snr[NCAND];
           int srowi[32]; float sw[32]; float red1[8], red2[8];
           float sqt[DIM]; float smg[2048]; } t;                            // ~14 KB
};

// device-scope grid barrier; cnt zeroed by hipMemsetAsync each launch; gen monotonic.
__device__ __forceinline__ void gridbar(u32* cnt, u32* gen) {
  __syncthreads();
  if (threadIdx.x == 0) {
    __threadfence();
    u32 g0 = __hip_atomic_load(gen, __ATOMIC_RELAXED, __HIP_MEMORY_SCOPE_AGENT);
    u32 old = __hip_atomic_fetch_add(cnt, 1u, __ATOMIC_ACQ_REL, __HIP_MEMORY_SCOPE_AGENT);
    if (old == NBLK - 1u) {
      __hip_atomic_store(cnt, 0u, __ATOMIC_RELAXED, __HIP_MEMORY_SCOPE_AGENT);
      __hip_atomic_fetch_add(gen, 1u, __ATOMIC_ACQ_REL, __HIP_MEMORY_SCOPE_AGENT);
    } else {
      while (__hip_atomic_load(gen, __ATOMIC_ACQUIRE, __HIP_MEMORY_SCOPE_AGENT) == g0)
        __builtin_amdgcn_s_sleep(2);
    }
    __threadfence();
  }
  __syncthreads();
}

// small fp32 NT-GEMM phase, split-K4: out[m][n] = sum_k A[m][k]*B[n][k]
// block b: n0=(b&15)*64, m0=((b>>4)&3)*64, kz=b>>6; 512 thr, 2x4 acc/thread.
__device__ __forceinline__ void small_gemm(const float* __restrict__ A,
                                           const float* __restrict__ B,
                                           float* __restrict__ partial,
                                           SMEM* sm, int b, int tid) {
  const int n0 = (b & 15) * 64;
  const int m0 = ((b >> 4) & 3) * 64;
  const int kz = (b >> 6) & 3;
  const int ar = tid & 63;
  const int kq = (tid >> 6) * 4;
  const int tx = tid & 15, ty = tid >> 4;
  float acc[2][4] = {};
  const float* ag = A + (size_t)(m0 + ar) * DIM + kz * 256 + kq;
  const float* bg = B + (size_t)(n0 + ar) * DIM + kz * 256 + kq;
  f32x4 av = *(const f32x4*)ag;
  f32x4 bv = *(const f32x4*)bg;
#pragma unroll
  for (int i = 0; i < 4; ++i) {
    sm->g.sAT[0][kq + i][ar] = av[i];
    sm->g.sBT[0][kq + i][ar] = bv[i];
  }
  __syncthreads();
  for (int kb = 0; kb < 8; ++kb) {
    const int cur = kb & 1;
    if (kb + 1 < 8) {
      av = *(const f32x4*)(ag + (kb + 1) * 32);
      bv = *(const f32x4*)(bg + (kb + 1) * 32);
    }
#pragma unroll
    for (int kk = 0; kk < 32; ++kk) {
      const f32x2 a2 = *(const f32x2*)&sm->g.sAT[cur][kk][ty * 2];
      const f32x4 b4 = *(const f32x4*)&sm->g.sBT[cur][kk][tx * 4];
#pragma unroll
      for (int i = 0; i < 2; ++i)
#pragma unroll
        for (int j = 0; j < 4; ++j) acc[i][j] += a2[i] * b4[j];
    }
    if (kb + 1 < 8) {
#pragma unroll
      for (int i = 0; i < 4; ++i) {
        sm->g.sAT[cur ^ 1][kq + i][ar] = av[i];
        sm->g.sBT[cur ^ 1][kq + i][ar] = bv[i];
      }
    }
    __syncthreads();
  }
#pragma unroll
  for (int i = 0; i < 2; ++i) {
    f32x4 ov = {acc[i][0], acc[i][1], acc[i][2], acc[i][3]};
    *(f32x4*)(partial + (size_t)kz * 262144u + (size_t)(m0 + ty * 2 + i) * DIM + n0 + tx * 4) = ov;
  }
}

// sum 4 split-K slabs + bias + relu; f32x2 per thread over the full grid
__device__ __forceinline__ void reduce_phase(const float* __restrict__ partial,
                                             const float* __restrict__ bias,
                                             float* __restrict__ outf,
                                             u16* __restrict__ outb, int gid) {
  const int e = gid * 2;
  const int n = e & (DIM - 1);
  f32x2 s = *(const f32x2*)(partial + e);
  s += *(const f32x2*)(partial + 262144u + e);
  s += *(const f32x2*)(partial + 2u * 262144u + e);
  s += *(const f32x2*)(partial + 3u * 262144u + e);
  s += *(const f32x2*)(bias + n);
  s[0] = fmaxf(s[0], 0.f);
  s[1] = fmaxf(s[1], 0.f);
  *(f32x2*)(outf + e) = s;
  if (outb) {
    u32 h = cvtpk(s[0], s[1]);
    *(u32*)(outb + e) = h;
  }
}

__global__ __launch_bounds__(NTHR) void mega(
    const float* __restrict__ query, const float* __restrict__ keys,
    const float* __restrict__ Wenc, const float* __restrict__ benc,
    const float* __restrict__ Wd, const float* __restrict__ bd,
    const float* __restrict__ lng, const float* __restrict__ lnb,
    const float* __restrict__ Wc, const float* __restrict__ bc,
    float* __restrict__ q, u16* __restrict__ qb,
    float* __restrict__ par1, float* __restrict__ par2, u16* __restrict__ sim,
    u32* __restrict__ bar, float* __restrict__ out)
{
  __shared__ SMEM smem;
  SMEM* const sm = &smem;
  const int tid = threadIdx.x;
  const int b = blockIdx.x;
  const int lane = tid & 63, wave = tid >> 6;
  u32* cnt = bar;
  u32* gen = bar + 32;

  // ---- P1: q_partial = query @ Wenc^T
  small_gemm(query, Wenc, par1, sm, b, tid);
  gridbar(cnt, gen);
  // ---- R1: q = relu(sum + benc); qb = bf16(q)
  reduce_phase(par1, benc, q, qb, b * NTHR + tid);
  gridbar(cnt, gen);
  // ---- P2: qt_partial = q @ Wd^T  (consumed only in P4; ordered by the P3 barrier)
  small_gemm(q, Wd, par2, sm, b, tid);

  // ---- P3: sim = bf16( (q . key_n) / max(||key_n||,1e-8) ), 2 stripes of 128 keys
  {
    const int a_r = tid >> 1;
    const int a_h = (tid & 1) * 16;
    const u16* agp = qb + (size_t)a_r * DIM + a_h;
    const int a_ws = a_r * SROW + a_h;
    const int b_r = tid >> 2;
    const int b_q = (tid & 3) * 8;
    const int b_ws = b_r * SROW + b_q;
    const int wm = (wave >> 1) * 64;
    const int wn = (wave & 1) * 64;
    const int lr = lane & 15;
    const int lk = (lane >> 4) * 8;
    const int l4 = (lane >> 4) * 4;

    for (int s = 0; s < 2; ++s) {
      const int n0 = (b * 2 + s) * 128;
      const float* bgp = keys + (size_t)(n0 + b_r) * DIM + b_q;
      float nrm = 0.f;
      f32x4 acc[4][4];
#pragma unroll
      for (int i = 0; i < 4; ++i)
#pragma unroll
        for (int j = 0; j < 4; ++j) acc[i][j] = (f32x4){0.f, 0.f, 0.f, 0.f};

      f32x4 b00, b01, b10, b11, b20, b21, b30, b31;
      u32x4 a00, a01, a10, a11;

#define LOADB(B0, B1, T) do { \
    B0 = *(const f32x4*)(bgp + (size_t)(T) * 32); \
    B1 = *(const f32x4*)(bgp + (size_t)(T) * 32 + 4); \
  } while (0)
#define LOADA(A0, A1, T) do { \
    A0 = *(const u32x4*)(agp + (size_t)(T) * 32); \
    A1 = *(const u32x4*)(agp + (size_t)(T) * 32 + 8); \
  } while (0)
#define WRITE(B0, B1, A0, A1, BUF) do { \
    nrm += B0[0]*B0[0] + B0[1]*B0[1] + B0[2]*B0[2] + B0[3]*B0[3]; \
    nrm += B1[0]*B1[0] + B1[1]*B1[1] + B1[2]*B1[2] + B1[3]*B1[3]; \
    u32x4 bp; \
    bp.x = cvtpk(B0[0], B0[1]); bp.y = cvtpk(B0[2], B0[3]); \
    bp.z = cvtpk(B1[0], B1[1]); bp.w = cvtpk(B1[2], B1[3]); \
    *(u32x4*)&sm->s.sB[BUF][b_ws] = bp; \
    *(u32x4*)&sm->s.sA[BUF][a_ws] = A0; \
    *(u32x4*)&sm->s.sA[BUF][a_ws + 8] = A1; \
  } while (0)
#define COMPUTE(BUF) do { \
    bf16x8 af[4], bfr[4]; \
    _Pragma("unroll") \
    for (int f = 0; f < 4; ++f) { \
      af[f]  = *(const bf16x8*)&sm->s.sA[BUF][(wm + f * 16 + lr) * SROW + lk]; \
      bfr[f] = *(const bf16x8*)&sm->s.sB[BUF][(wn + f * 16 + lr) * SROW + lk]; \
    } \
    _Pragma("unroll") \
    for (int i = 0; i < 4; ++i) \
      _Pragma("unroll") \
      for (int j = 0; j < 4; ++j) \
        acc[i][j] = __builtin_amdgcn_mfma_f32_16x16x32_bf16(af[i], bfr[j], acc[i][j], 0, 0, 0); \
  } while (0)

      LOADB(b00, b01, 0); LOADB(b10, b11, 1); LOADB(b20, b21, 2); LOADB(b30, b31, 3);
      LOADA(a00, a01, 0); LOADA(a10, a11, 1);
      WRITE(b00, b01, a00, a01, 0);
      __syncthreads();

      for (int tt = 0; tt < 32; tt += 4) {
        if (tt + 4 < 32) LOADB(b00, b01, tt + 4);
        LOADA(a00, a01, tt + 2);
        COMPUTE(0);
        WRITE(b10, b11, a10, a11, 1);
        __syncthreads();
        if (tt + 5 < 32) LOADB(b10, b11, tt + 5);
        LOADA(a10, a11, tt + 3);
        COMPUTE(1);
        WRITE(b20, b21, a00, a01, 0);
        __syncthreads();
        if (tt + 6 < 32) LOADB(b20, b21, tt + 6);
        if (tt + 4 < 32) LOADA(a00, a01, tt + 4);
        COMPUTE(0);
        WRITE(b30, b31, a10, a11, 1);
        __syncthreads();
        if (tt + 7 < 32) LOADB(b30, b31, tt + 7);
        if (tt + 5 < 32) LOADA(a10, a11, tt + 5);
        COMPUTE(1);
        if (tt + 4 < 32) WRITE(b00, b01, a00, a01, 0);
        __syncthreads();
      }
#undef LOADB
#undef LOADA
#undef WRITE
#undef COMPUTE

      nrm += __shfl_xor(nrm, 1);
      nrm += __shfl_xor(nrm, 2);
      if ((tid & 3) == 0) sm->s.snorm[b_r] = nrm;
      __syncthreads();

#pragma unroll
      for (int j = 0; j < 4; ++j) {
        const int nl = wn + j * 16 + lr;
        const float scl = 1.f / fmaxf(sqrtf(sm->s.snorm[nl]), 1e-8f);
        const size_t ng = (size_t)(n0 + nl);
#pragma unroll
        for (int i = 0; i < 4; ++i) {
          const int mb = wm + i * 16 + l4;
#pragma unroll
          for (int r = 0; r < 4; ++r) {
            sim[(size_t)(mb + r) * NKEYS + ng] = f2bf(acc[i][j][r] * scl);
          }
        }
      }
      __syncthreads();
    }
  }
  gridbar(cnt, gen);

  // ---- P4: qt-row reduce -> top-64 -> exact rescore -> top-32 softmax -> LN -> classifier
  {
    const int m = b;

    // qt[m] = relu(sum of par2 slabs row m + bd), into LDS
    {
      const int e = tid * 2;
      f32x2 s = *(const f32x2*)(par2 + (size_t)m * DIM + e);
      s += *(const f32x2*)(par2 + 262144u + (size_t)m * DIM + e);
      s += *(const f32x2*)(par2 + 2u * 262144u + (size_t)m * DIM + e);
      s += *(const f32x2*)(par2 + 3u * 262144u + (size_t)m * DIM + e);
      s += *(const f32x2*)(bd + e);
      sm->t.sqt[e]     = fmaxf(s[0], 0.f);
      sm->t.sqt[e + 1] = fmaxf(s[1], 0.f);
    }
    __syncthreads();

    const u32x4* row = (const u32x4*)(sim + (size_t)m * NKEYS);
    u32 ku[16][4];
#pragma unroll
    for (int i = 0; i < 16; ++i) {
      const u32x4 v = row[i * 512 + tid];
#pragma unroll
      for (int c = 0; c < 4; ++c) {
        u32 lo = v[c] & 0xFFFFu, hi = v[c] >> 16;
        lo ^= (lo & 0x8000u) ? 0xFFFFu : 0x8000u;
        hi ^= (hi & 0x8000u) ? 0xFFFFu : 0x8000u;
        ku[i][c] = lo | (hi << 16);
      }
    }
    int lo_b = 0, hi_b = 65536;
    while (hi_b - lo_b > 1) {
      const u32 mid = (u32)((lo_b + hi_b) >> 1);
      int c = 0;
#pragma unroll
      for (int i = 0; i < 16; ++i)
#pragma unroll
        for (int k = 0; k < 4; ++k) {
          const u32 x = ku[i][k];
          c += ((x & 0xFFFFu) >= mid) ? 1 : 0;
          c += ((x >> 16) >= mid) ? 1 : 0;
        }
#pragma unroll
      for (int j = 32; j; j >>= 1) c += __shfl_xor(c, j);
      if ((tid & 63) == 0) sm->t.redc[tid >> 6] = c;
      __syncthreads();
      int tot = 0;
#pragma unroll
      for (int w = 0; w < 8; ++w) tot += sm->t.redc[w];
      if (tot >= NCAND) lo_b = (int)mid; else hi_b = (int)mid;
      __syncthreads();
    }
    const u32 tau = (u32)lo_b;

    int ch = 0;
#pragma unroll
    for (int i = 0; i < 16; ++i)
#pragma unroll
      for (int k = 0; k < 4; ++k) {
        const u32 x = ku[i][k];
        ch += ((x & 0xFFFFu) > tau) ? 1 : 0;
        ch += ((x >> 16) > tau) ? 1 : 0;
      }
#pragma unroll
    for (int j = 32; j; j >>= 1) ch += __shfl_xor(ch, j);
    if ((tid & 63) == 0) sm->t.redc[tid >> 6] = ch;
    if (tid == 0) { sm->t.sc1 = 0; sm->t.sc2 = 0; }
    __syncthreads();
    int nhi = 0;
#pragma unroll
    for (int w = 0; w < 8; ++w) nhi += sm->t.redc[w];

#pragma unroll
    for (int i = 0; i < 16; ++i)
#pragma unroll
      for (int k = 0; k < 4; ++k) {
        const int nb = (i * 512 + tid) * 8 + k * 2;
        const u32 x = ku[i][k];
        const u32 l = x & 0xFFFFu, h = x >> 16;
        if (l > tau) { int p = atomicAdd(&sm->t.sc1, 1); sm->t.clist[p] = nb; }
        else if (l == tau) { int p = atomicAdd(&sm->t.sc2, 1); if (nhi + p < NCAND) sm->t.clist[nhi + p] = nb; }
        if (h > tau) { int p = atomicAdd(&sm->t.sc1, 1); sm->t.clist[p] = nb + 1; }
        else if (h == tau) { int p = atomicAdd(&sm->t.sc2, 1); if (nhi + p < NCAND) sm->t.clist[nhi + p] = nb + 1; }
      }
    __syncthreads();

    // exact fp32 rescore (8 candidates per wave)
    f32x4 q4[4], qt4[4];
#pragma unroll
    for (int i = 0; i < 4; ++i) {
      q4[i]  = *(const f32x4*)(q + (size_t)m * DIM + i * 256 + lane * 4);
      qt4[i] = *(const f32x4*)&sm->t.sqt[i * 256 + lane * 4];
    }
    for (int ci = 0; ci < 8; ++ci) {
      const int c = wave * 8 + ci;
      const float* kr = keys + (size_t)sm->t.clist[c] * DIM;
      float dq = 0.f, dt = 0.f, ss = 0.f;
#pragma unroll
      for (int i = 0; i < 4; ++i) {
        const f32x4 kv = *(const f32x4*)(kr + i * 256 + lane * 4);
#pragma unroll
        for (int e = 0; e < 4; ++e) {
          dq += kv[e] * q4[i][e];
          dt += kv[e] * qt4[i][e];
          ss += kv[e] * kv[e];
        }
      }
#pragma unroll
      for (int j = 32; j; j >>= 1) {
        dq += __shfl_xor(dq, j);
        dt += __shfl_xor(dt, j);
        ss += __shfl_xor(ss, j);
      }
      if (lane == 0) { sm->t.sdq[c] = dq; sm->t.sdqt[c] = dt; sm->t.snr[c] = ss; }
    }
    __syncthreads();

    // top-32 of 64 (bitonic on wave 0) + softmax weights
    if (wave == 0) {
      float v = sm->t.sdq[lane] / fmaxf(sqrtf(sm->t.snr[lane]), 1e-8f);
      int p = lane;
#pragma unroll
      for (int k = 2; k <= 64; k <<= 1)
#pragma unroll
        for (int j = k >> 1; j > 0; j >>= 1) {
          const float ov = __shfl_xor(v, j);
          const int op = __shfl_xor(p, j);
          const bool tl = ((lane & j) == 0) == ((lane & k) == 0);
          const bool take = tl ? (ov > v) : (ov < v);
          if (take) { v = ov; p = op; }
        }
      float sc = (lane < 32) ? sm->t.sdqt[p] : -3.4e38f;
      float mx = sc;
#pragma unroll
      for (int j = 16; j; j >>= 1) mx = fmaxf(mx, __shfl_xor(mx, j));
      const float e = (lane < 32) ? expf(sc - mx) : 0.f;
      float ssum = e;
#pragma unroll
      for (int j = 16; j; j >>= 1) ssum += __shfl_xor(ssum, j);
      if (lane < 32) { sm->t.sw[lane] = e / ssum; sm->t.srowi[lane] = sm->t.clist[p]; }
    }
    __syncthreads();

    // attention + residual + LayerNorm
    const int d0 = tid * 2;
    f32x2 at = {0.f, 0.f};
    for (int j = 0; j < 32; ++j) {
      const float wj = sm->t.sw[j];
      const f32x2 kv = *(const f32x2*)(keys + (size_t)sm->t.srowi[j] * DIM + d0);
      at += wj * kv;
    }
    const f32x2 qv = *(const f32x2*)(q + (size_t)m * DIM + d0);
    const f32x2 x = at + qv;
    float s1 = x[0] + x[1];
#pragma unroll
    for (int j = 32; j; j >>= 1) s1 += __shfl_xor(s1, j);
    if (lane == 0) sm->t.red1[wave] = s1;
    __syncthreads();
    float mu = 0.f;
#pragma unroll
    for (int w = 0; w < 8; ++w) mu += sm->t.red1[w];
    mu *= (1.f / 1024.f);
    const f32x2 xc = x - mu;
    float s2 = xc[0] * xc[0] + xc[1] * xc[1];
#pragma unroll
    for (int j = 32; j; j >>= 1) s2 += __shfl_xor(s2, j);
    if (lane == 0) sm->t.red2[wave] = s2;
    __syncthreads();
    float var = 0.f;
#pragma unroll
    for (int w = 0; w < 8; ++w) var += sm->t.red2[w];
    var *= (1.f / 1024.f);
    const float rstd = rsqrtf(var + 1e-5f);
    const f32x2 g = *(const f32x2*)(lng + d0);
    const f32x2 bb = *(const f32x2*)(lnb + d0);
    const f32x2 ma = xc * rstd * g + bb;
    *(f32x2*)&sm->t.smg[d0] = qv;
    *(f32x2*)&sm->t.smg[1024 + d0] = ma;
    __syncthreads();

    // classifier
    for (int c = wave; c < NCLS; c += 8) {
      const float* w = Wc + (size_t)c * 2048;
      float a = 0.f;
#pragma unroll
      for (int i = 0; i < 8; ++i) {
        const f32x4 wv = *(const f32x4*)(w + i * 256 + lane * 4);
        const f32x4 mv = *(const f32x4*)&sm->t.smg[i * 256 + lane * 4];
#pragma unroll
        for (int e = 0; e < 4; ++e) a += wv[e] * mv[e];
      }
#pragma unroll
      for (int j = 32; j; j >>= 1) a += __shfl_xor(a, j);
      if (lane == 0) out[(size_t)m * NCLS + c] = a + bc[c];
    }
  }
}

extern "C" void kernel_launch(void* const* d_in, const int* in_sizes, int n_in,
                              void* d_out, int out_size, void* d_ws, size_t ws_size,
                              hipStream_t stream)
{
  const float* query = (const float*)d_in[1];
  const float* keys  = (const float*)d_in[2];
  const float* Wenc  = (const float*)d_in[3];
  const float* benc  = (const float*)d_in[4];
  const float* Wd    = (const float*)d_in[5];
  const float* bd    = (const float*)d_in[6];
  const float* lng   = (const float*)d_in[7];
  const float* lnb   = (const float*)d_in[8];
  const float* Wcls  = (const float*)d_in[9];
  const float* bcls  = (const float*)d_in[10];
  float* out = (float*)d_out;
  char* ws = (char*)d_ws;

  // workspace layout (bytes); par slabs alias the head of sim (dead before P3 writes)
  float* q   = (float*)(ws + 0);              // 1 MB
  u16*   qb  = (u16*)(ws + 1048576u);         // 0.5 MB
  u32*   bar = (u32*)(ws + 1572864u);         // 4 KB (cnt @ +0, gen @ +128)
  char*  big = ws + 1576960u;                 // 32 MB sim
  u16*   sim = (u16*)big;
  float* par1 = (float*)big;                  // 4 MB (P1 slabs, dead after R1)
  float* par2 = (float*)(big + 4194304u);     // 4 MB (P2 slabs, read in P4 before any
                                              //  sim row m columns 2M..4M... NOTE: see below)

  // par2 aliases sim bytes [4 MB, 8 MB) = sim rows 32..63's columns? No: sim is
  // row-major [256][65536] u16 = 128 KB/row; bytes 4-8 MB are rows 32..63 ENTIRELY.
  // P4 block m in [32,64) reads sim row m AND par2 — both needed => conflict!
  // Fix: place par2 AFTER sim (ws has plenty: sim ends at 1576960+33554432).
  par2 = (float*)(ws + 35131392u);            // 4 MB, disjoint from sim

  hipMemsetAsync(bar, 0, 256, stream);
  mega<<<NBLK, NTHR, 0, stream>>>(query, keys, Wenc, benc, Wd, bd, lng, lnb,
                                  Wcls, bcls, q, qb, par1, par2, sim, bar, out);
}

// Round 8
// 185.201 us; speedup vs baseline: 1.9723x; 1.6214x over previous
//
#include <hip/hip_runtime.h>
#include <stdint.h>

typedef unsigned short u16;
typedef unsigned int u32;
typedef __attribute__((ext_vector_type(2))) float f32x2;
typedef __attribute__((ext_vector_type(4))) float f32x4;
typedef __attribute__((ext_vector_type(4))) u32 u32x4;
typedef __attribute__((ext_vector_type(2))) u32 u32x2;
typedef __attribute__((ext_vector_type(8))) short bf16x8;

#define NKEYS 65536
#define DIM 1024
#define BQ 256
#define NCLS 103
#define NCAND 64
#define SROW 40   // padded LDS row stride in u16 (80 B = 5 bank-quads, coprime with 8)

__device__ __forceinline__ u16 f2bf(float x) {
  u32 u = __float_as_uint(x);
  u = u + 0x7FFFu + ((u >> 16) & 1u);
  return (u16)(u >> 16);
}
// packed f32x2 -> bf16x2; used identically on A and B packing so any intra-pair
// k-permutation cancels in the dot product.
__device__ __forceinline__ u32 cvtpk(float lo, float hi) {
  u32 d;
  asm("v_cvt_pk_bf16_f32 %0, %1, %2" : "=v"(d) : "v"(lo), "v"(hi));
  return d;
}

// Raw barrier WITHOUT the compiler's vmcnt(0) drain (T3/T4 minimum form):
// own ds ops committed (lgkmcnt(0)), then s_barrier; sched_barrier(0) pins
// ordering so next phase's ds_reads can't hoist above (rule #18).
#define RBAR() do { \
    asm volatile("s_waitcnt lgkmcnt(0)" ::: "memory"); \
    __builtin_amdgcn_s_barrier(); \
    __builtin_amdgcn_sched_barrier(0); \
  } while (0)

// ---------------- small fp32 GEMM: out[m][n] = sum_k A[m][k]*B[n][k], split-K partials
// Double-buffered LDS: next k-slice loads while current computes.
__global__ __launch_bounds__(256) void gemm_nt_f32(
    const float* __restrict__ A, const float* __restrict__ B,
    float* __restrict__ partial)
{
  __shared__ float sAT[2][16][68];
  __shared__ float sBT[2][16][68];
  const int tid = threadIdx.x;
  const int n0 = blockIdx.x * 64;
  const int m0 = blockIdx.y * 64;
  const int kz = blockIdx.z;
  const int r = tid & 63, kq = tid >> 6;
  const int tx = tid & 15, ty = tid >> 4;
  float acc[4][4] = {};

  const float* ag = A + (size_t)(m0 + r) * DIM + kz * 256 + kq * 4;
  const float* bg = B + (size_t)(n0 + r) * DIM + kz * 256 + kq * 4;

  f32x4 av = *(const f32x4*)(ag);
  f32x4 bv = *(const f32x4*)(bg);
#pragma unroll
  for (int i = 0; i < 4; ++i) {
    sAT[0][kq * 4 + i][r] = av[i];
    sBT[0][kq * 4 + i][r] = bv[i];
  }
  __syncthreads();

  for (int kb = 0; kb < 16; ++kb) {
    const int cur = kb & 1;
    if (kb + 1 < 16) {
      av = *(const f32x4*)(ag + (kb + 1) * 16);
      bv = *(const f32x4*)(bg + (kb + 1) * 16);
    }
#pragma unroll
    for (int kk = 0; kk < 16; ++kk) {
      const f32x4 a4 = *(const f32x4*)&sAT[cur][kk][ty * 4];
      const f32x4 b4 = *(const f32x4*)&sBT[cur][kk][tx * 4];
#pragma unroll
      for (int i = 0; i < 4; ++i)
#pragma unroll
        for (int j = 0; j < 4; ++j) acc[i][j] += a4[i] * b4[j];
    }
    if (kb + 1 < 16) {
#pragma unroll
      for (int i = 0; i < 4; ++i) {
        sAT[cur ^ 1][kq * 4 + i][r] = av[i];
        sBT[cur ^ 1][kq * 4 + i][r] = bv[i];
      }
    }
    __syncthreads();
  }
#pragma unroll
  for (int i = 0; i < 4; ++i) {
    f32x4 ov = {acc[i][0], acc[i][1], acc[i][2], acc[i][3]};
    *(f32x4*)(partial + (size_t)kz * 262144u + (size_t)(m0 + ty * 4 + i) * DIM + n0 + tx * 4) = ov;
  }
}

// ---------------- sum split-K partials + bias + relu (optionally also emit bf16)
__global__ __launch_bounds__(256) void reduce_bias_relu(
    const float* __restrict__ partial, const float* __restrict__ bias,
    float* __restrict__ outf, u16* __restrict__ outb, const int wbf)
{
  const int i4 = blockIdx.x * 256 + threadIdx.x;
  const int e = i4 * 4;
  const int n = e & (DIM - 1);
  f32x4 s = *(const f32x4*)(partial + e);
  s += *(const f32x4*)(partial + 262144u + e);
  s += *(const f32x4*)(partial + 2u * 262144u + e);
  s += *(const f32x4*)(partial + 3u * 262144u + e);
  s += *(const f32x4*)(bias + n);
#pragma unroll
  for (int i = 0; i < 4; ++i) s[i] = fmaxf(s[i], 0.f);
  *(f32x4*)(outf + e) = s;
  if (wbf) {
    u32x2 h = {cvtpk(s[0], s[1]), cvtpk(s[2], s[3])};
    *(u32x2*)(outb + e) = h;
  }
}

// ---------------- big bf16 MFMA GEMM: sim[m][n] = (q[m]. key[n]) / max(||key[n]||,1e-8)
// BM=256 (keys read exactly once), BN=128, BK=32, 512 threads.
// 4-deep B-side register prefetch (HBM), 2-deep A-side (L2-hot qb).
// Raw barriers (no vmcnt drain) keep prefetched loads in flight across phases;
// waves_per_eu(2,2) gives the allocator the full 256-VGPR budget (no spills).
__global__ __launch_bounds__(512) __attribute__((amdgpu_waves_per_eu(2, 2)))
void simgemm(
    const float* __restrict__ keys, const u16* __restrict__ qb,
    u16* __restrict__ sim)
{
  __shared__ u16 sA[2][256 * SROW];
  __shared__ u16 sB[2][128 * SROW];
  __shared__ float snorm[128];
  const int tid = threadIdx.x;
  const int n0 = blockIdx.x * 128;

  const int a_r = tid >> 1;
  const int a_h = (tid & 1) * 16;
  const u16* agp = qb + (size_t)a_r * DIM + a_h;
  const int a_ws = a_r * SROW + a_h;

  const int b_r = tid >> 2;
  const int b_q = (tid & 3) * 8;
  const float* bgp = keys + (size_t)(n0 + b_r) * DIM + b_q;
  const int b_ws = b_r * SROW + b_q;

  const int lane = tid & 63, wave = tid >> 6;
  const int wm = (wave >> 1) * 64;
  const int wn = (wave & 1) * 64;
  const int lr = lane & 15;
  const int lk = (lane >> 4) * 8;
  const int l4 = (lane >> 4) * 4;

  float nrm = 0.f;
  f32x4 acc[4][4];
#pragma unroll
  for (int i = 0; i < 4; ++i)
#pragma unroll
    for (int j = 0; j < 4; ++j) acc[i][j] = (f32x4){0.f, 0.f, 0.f, 0.f};

  // named register stage slots: B depth-4, A depth-2
  f32x4 b00, b01, b10, b11, b20, b21, b30, b31;
  u32x4 a00, a01, a10, a11;

#define LOADB(B0, B1, T) do { \
    B0 = *(const f32x4*)(bgp + (size_t)(T) * 32); \
    B1 = *(const f32x4*)(bgp + (size_t)(T) * 32 + 4); \
  } while (0)
#define LOADA(A0, A1, T) do { \
    A0 = *(const u32x4*)(agp + (size_t)(T) * 32); \
    A1 = *(const u32x4*)(agp + (size_t)(T) * 32 + 8); \
  } while (0)
#define WRITE(B0, B1, A0, A1, BUF) do { \
    nrm += B0[0]*B0[0] + B0[1]*B0[1] + B0[2]*B0[2] + B0[3]*B0[3]; \
    nrm += B1[0]*B1[0] + B1[1]*B1[1] + B1[2]*B1[2] + B1[3]*B1[3]; \
    u32x4 bp; \
    bp.x = cvtpk(B0[0], B0[1]); bp.y = cvtpk(B0[2], B0[3]); \
    bp.z = cvtpk(B1[0], B1[1]); bp.w = cvtpk(B1[2], B1[3]); \
    *(u32x4*)&sB[BUF][b_ws] = bp; \
    *(u32x4*)&sA[BUF][a_ws] = A0; \
    *(u32x4*)&sA[BUF][a_ws + 8] = A1; \
  } while (0)
#define COMPUTE(BUF) do { \
    bf16x8 af[4], bfr[4]; \
    _Pragma("unroll") \
    for (int f = 0; f < 4; ++f) { \
      af[f]  = *(const bf16x8*)&sA[BUF][(wm + f * 16 + lr) * SROW + lk]; \
      bfr[f] = *(const bf16x8*)&sB[BUF][(wn + f * 16 + lr) * SROW + lk]; \
    } \
    _Pragma("unroll") \
    for (int i = 0; i < 4; ++i) \
      _Pragma("unroll") \
      for (int j = 0; j < 4; ++j) \
        acc[i][j] = __builtin_amdgcn_mfma_f32_16x16x32_bf16(af[i], bfr[j], acc[i][j], 0, 0, 0); \
  } while (0)

  // prologue: B tiles 0-3 in flight, A tiles 0-1; tile 0 -> LDS0
  LOADB(b00, b01, 0); LOADB(b10, b11, 1); LOADB(b20, b21, 2); LOADB(b30, b31, 3);
  LOADA(a00, a01, 0); LOADA(a10, a11, 1);
  WRITE(b00, b01, a00, a01, 0);
  RBAR();

  for (int tt = 0; tt < 32; tt += 4) {
    // half0: compute tile tt (L0)
    if (tt + 4 < 32) LOADB(b00, b01, tt + 4);
    LOADA(a00, a01, tt + 2);                    // tt+2 <= 30 always
    COMPUTE(0);
    WRITE(b10, b11, a10, a11, 1);               // tile tt+1 -> L1
    RBAR();
    // half1: compute tile tt+1 (L1)
    if (tt + 5 < 32) LOADB(b10, b11, tt + 5);
    LOADA(a10, a11, tt + 3);                    // tt+3 <= 31 always
    COMPUTE(1);
    WRITE(b20, b21, a00, a01, 0);               // tile tt+2 -> L0
    RBAR();
    // half2: compute tile tt+2 (L0)
    if (tt + 6 < 32) LOADB(b20, b21, tt + 6);
    if (tt + 4 < 32) LOADA(a00, a01, tt + 4);
    COMPUTE(0);
    WRITE(b30, b31, a10, a11, 1);               // tile tt+3 -> L1
    RBAR();
    // half3: compute tile tt+3 (L1)
    if (tt + 7 < 32) LOADB(b30, b31, tt + 7);
    if (tt + 5 < 32) LOADA(a10, a11, tt + 5);
    COMPUTE(1);
    if (tt + 4 < 32) WRITE(b00, b01, a00, a01, 0);  // tile tt+4 -> L0
    RBAR();
  }
#undef LOADB
#undef LOADA
#undef WRITE
#undef COMPUTE

  nrm += __shfl_xor(nrm, 1);
  nrm += __shfl_xor(nrm, 2);
  if ((tid & 3) == 0) snorm[b_r] = nrm;
  __syncthreads();

#pragma unroll
  for (int j = 0; j < 4; ++j) {
    const int nl = wn + j * 16 + lr;
    const float scl = 1.f / fmaxf(sqrtf(snorm[nl]), 1e-8f);
    const size_t ng = (size_t)(n0 + nl);
#pragma unroll
    for (int i = 0; i < 4; ++i) {
      const int mb = wm + i * 16 + l4;
#pragma unroll
      for (int r = 0; r < 4; ++r) {
        sim[(size_t)(mb + r) * NKEYS + ng] = f2bf(acc[i][j][r] * scl);
      }
    }
  }
}

// ---------------- fused: top-64 select + exact fp32 rescore + top-32 + softmax
// attention + LayerNorm + classifier. One block per query row, 512 threads.
__global__ __launch_bounds__(512) __attribute__((amdgpu_waves_per_eu(2, 2)))
void select_attn_cls(
    const u16* __restrict__ sim, const float* __restrict__ keys,
    const float* __restrict__ q, const float* __restrict__ qt,
    const float* __restrict__ ln_g, const float* __restrict__ ln_b,
    const float* __restrict__ Wc, const float* __restrict__ bc,
    float* __restrict__ out)
{
  __shared__ int redc[8];
  __shared__ int sc1, sc2;
  __shared__ int clist[NCAND];
  __shared__ float sdq[NCAND], sdqt[NCAND], snr[NCAND];
  __shared__ int srowi[32];
  __shared__ float sw[32];
  __shared__ float red1[8], red2[8];
  __shared__ float smg[2048];
  const int tid = threadIdx.x, lane = tid & 63, wave = tid >> 6;
  const int m = blockIdx.x;

  // ---- phase A: top-64 candidates via binary search on monotonic u16 keys
  const u32x4* row = (const u32x4*)(sim + (size_t)m * NKEYS);
  u32 ku[16][4];
#pragma unroll
  for (int i = 0; i < 16; ++i) {
    const u32x4 v = row[i * 512 + tid];
#pragma unroll
    for (int c = 0; c < 4; ++c) {
      u32 lo = v[c] & 0xFFFFu, hi = v[c] >> 16;
      lo ^= (lo & 0x8000u) ? 0xFFFFu : 0x8000u;
      hi ^= (hi & 0x8000u) ? 0xFFFFu : 0x8000u;
      ku[i][c] = lo | (hi << 16);
    }
  }
  int lo_b = 0, hi_b = 65536;
  while (hi_b - lo_b > 1) {
    const u32 mid = (u32)((lo_b + hi_b) >> 1);
    int c = 0;
#pragma unroll
    for (int i = 0; i < 16; ++i)
#pragma unroll
      for (int k = 0; k < 4; ++k) {
        const u32 x = ku[i][k];
        c += ((x & 0xFFFFu) >= mid) ? 1 : 0;
        c += ((x >> 16) >= mid) ? 1 : 0;
      }
#pragma unroll
    for (int j = 32; j; j >>= 1) c += __shfl_xor(c, j);
    if ((tid & 63) == 0) redc[tid >> 6] = c;
    __syncthreads();
    int tot = 0;
#pragma unroll
    for (int w = 0; w < 8; ++w) tot += redc[w];
    if (tot >= NCAND) lo_b = (int)mid; else hi_b = (int)mid;
    __syncthreads();
  }
  const u32 tau = (u32)lo_b;

  int ch = 0;
#pragma unroll
  for (int i = 0; i < 16; ++i)
#pragma unroll
    for (int k = 0; k < 4; ++k) {
      const u32 x = ku[i][k];
      ch += ((x & 0xFFFFu) > tau) ? 1 : 0;
      ch += ((x >> 16) > tau) ? 1 : 0;
    }
#pragma unroll
  for (int j = 32; j; j >>= 1) ch += __shfl_xor(ch, j);
  if ((tid & 63) == 0) redc[tid >> 6] = ch;
  if (tid == 0) { sc1 = 0; sc2 = 0; }
  __syncthreads();
  int nhi = 0;
#pragma unroll
  for (int w = 0; w < 8; ++w) nhi += redc[w];

#pragma unroll
  for (int i = 0; i < 16; ++i)
#pragma unroll
    for (int k = 0; k < 4; ++k) {
      const int nb = (i * 512 + tid) * 8 + k * 2;
      const u32 x = ku[i][k];
      const u32 l = x & 0xFFFFu, h = x >> 16;
      if (l > tau) { int p = atomicAdd(&sc1, 1); clist[p] = nb; }
      else if (l == tau) { int p = atomicAdd(&sc2, 1); if (nhi + p < NCAND) clist[nhi + p] = nb; }
      if (h > tau) { int p = atomicAdd(&sc1, 1); clist[p] = nb + 1; }
      else if (h == tau) { int p = atomicAdd(&sc2, 1); if (nhi + p < NCAND) clist[nhi + p] = nb + 1; }
    }
  __syncthreads();

  // ---- phase B: exact fp32 rescore of 64 candidates (8 per wave)
  f32x4 q4[4], qt4[4];
#pragma unroll
  for (int i = 0; i < 4; ++i) {
    q4[i]  = *(const f32x4*)(q  + (size_t)m * DIM + i * 256 + lane * 4);
    qt4[i] = *(const f32x4*)(qt + (size_t)m * DIM + i * 256 + lane * 4);
  }
  for (int ci = 0; ci < 8; ++ci) {
    const int c = wave * 8 + ci;
    const float* kr = keys + (size_t)clist[c] * DIM;
    float dq = 0.f, dt = 0.f, ss = 0.f;
#pragma unroll
    for (int i = 0; i < 4; ++i) {
      const f32x4 kv = *(const f32x4*)(kr + i * 256 + lane * 4);
#pragma unroll
      for (int e = 0; e < 4; ++e) {
        dq += kv[e] * q4[i][e];
        dt += kv[e] * qt4[i][e];
        ss += kv[e] * kv[e];
      }
    }
#pragma unroll
    for (int j = 32; j; j >>= 1) {
      dq += __shfl_xor(dq, j);
      dt += __shfl_xor(dt, j);
      ss += __shfl_xor(ss, j);
    }
    if (lane == 0) { sdq[c] = dq; sdqt[c] = dt; snr[c] = ss; }
  }
  __syncthreads();

  // ---- phase C: top-32 of 64 (bitonic on wave 0) + softmax weights
  if (wave == 0) {
    float v = sdq[lane] / fmaxf(sqrtf(snr[lane]), 1e-8f);
    int p = lane;
#pragma unroll
    for (int k = 2; k <= 64; k <<= 1)
#pragma unroll
      for (int j = k >> 1; j > 0; j >>= 1) {
        const float ov = __shfl_xor(v, j);
        const int op = __shfl_xor(p, j);
        const bool tl = ((lane & j) == 0) == ((lane & k) == 0);
        const bool take = tl ? (ov > v) : (ov < v);
        if (take) { v = ov; p = op; }
      }
    float sc = (lane < 32) ? sdqt[p] : -3.4e38f;
    float mx = sc;
#pragma unroll
    for (int j = 16; j; j >>= 1) mx = fmaxf(mx, __shfl_xor(mx, j));
    const float e = (lane < 32) ? expf(sc - mx) : 0.f;
    float s = e;
#pragma unroll
    for (int j = 16; j; j >>= 1) s += __shfl_xor(s, j);
    if (lane < 32) { sw[lane] = e / s; srowi[lane] = clist[p]; }
  }
  __syncthreads();

  // ---- phase D: attention + residual + LayerNorm (512 thr x f32x2)
  const int d0 = tid * 2;
  f32x2 at = {0.f, 0.f};
  for (int j = 0; j < 32; ++j) {
    const float wj = sw[j];
    const f32x2 kv = *(const f32x2*)(keys + (size_t)srowi[j] * DIM + d0);
    at += wj * kv;
  }
  const f32x2 qv = *(const f32x2*)(q + (size_t)m * DIM + d0);
  const f32x2 x = at + qv;
  float s1 = x[0] + x[1];
#pragma unroll
  for (int j = 32; j; j >>= 1) s1 += __shfl_xor(s1, j);
  if (lane == 0) red1[wave] = s1;
  __syncthreads();
  float mu = 0.f;
#pragma unroll
  for (int w = 0; w < 8; ++w) mu += red1[w];
  mu *= (1.f / 1024.f);
  const f32x2 xc = x - mu;
  float s2 = xc[0] * xc[0] + xc[1] * xc[1];
#pragma unroll
  for (int j = 32; j; j >>= 1) s2 += __shfl_xor(s2, j);
  if (lane == 0) red2[wave] = s2;
  __syncthreads();
  float var = 0.f;
#pragma unroll
  for (int w = 0; w < 8; ++w) var += red2[w];
  var *= (1.f / 1024.f);
  const float rstd = rsqrtf(var + 1e-5f);
  const f32x2 g = *(const f32x2*)(ln_g + d0);
  const f32x2 b = *(const f32x2*)(ln_b + d0);
  const f32x2 ma = xc * rstd * g + b;
  *(f32x2*)&smg[d0] = qv;
  *(f32x2*)&smg[1024 + d0] = ma;
  __syncthreads();

  // ---- phase E: classifier row (merged in LDS, Wc streamed from L2)
  for (int c = wave; c < NCLS; c += 8) {
    const float* w = Wc + (size_t)c * 2048;
    float a = 0.f;
#pragma unroll
    for (int i = 0; i < 8; ++i) {
      const f32x4 wv = *(const f32x4*)(w + i * 256 + lane * 4);
      const f32x4 mv = *(const f32x4*)&smg[i * 256 + lane * 4];
#pragma unroll
      for (int e = 0; e < 4; ++e) a += wv[e] * mv[e];
    }
#pragma unroll
    for (int j = 32; j; j >>= 1) a += __shfl_xor(a, j);
    if (lane == 0) out[(size_t)m * NCLS + c] = a + bc[c];
  }
}

extern "C" void kernel_launch(void* const* d_in, const int* in_sizes, int n_in,
                              void* d_out, int out_size, void* d_ws, size_t ws_size,
                              hipStream_t stream)
{
  const float* query = (const float*)d_in[1];
  const float* keys  = (const float*)d_in[2];
  const float* Wenc  = (const float*)d_in[3];
  const float* benc  = (const float*)d_in[4];
  const float* Wd    = (const float*)d_in[5];
  const float* bd    = (const float*)d_in[6];
  const float* lng   = (const float*)d_in[7];
  const float* lnb   = (const float*)d_in[8];
  const float* Wcls  = (const float*)d_in[9];
  const float* bcls  = (const float*)d_in[10];
  float* out = (float*)d_out;
  char* ws = (char*)d_ws;

  // workspace layout (bytes)
  float* q   = (float*)(ws + 0);            // 1 MB
  float* qt  = (float*)(ws + 1048576u);     // 1 MB
  u16*   qb  = (u16*)(ws + 2097152u);       // 0.5 MB
  char*  big = ws + 2621440u;               // 32 MB sim (aliased by 4 MB split-K partials)
  float* par = (float*)big;
  u16*   sim = (u16*)big;

  gemm_nt_f32<<<dim3(16, 4, 4), 256, 0, stream>>>(query, Wenc, par);
  reduce_bias_relu<<<256, 256, 0, stream>>>(par, benc, q, qb, 1);
  gemm_nt_f32<<<dim3(16, 4, 4), 256, 0, stream>>>(q, Wd, par);
  reduce_bias_relu<<<256, 256, 0, stream>>>(par, bd, qt, qb, 0);
  simgemm<<<dim3(512), 512, 0, stream>>>(keys, qb, sim);
  select_attn_cls<<<256, 512, 0, stream>>>(sim, keys, q, qt, lng, lnb, Wcls, bcls, out);
}